// Round 9
// baseline (468.294 us; speedup 1.0000x reference)
//
#include <hip/hip_runtime.h>
#include <hip/hip_fp16.h>
#include <cstddef>

#define NN 100000
#define NE 800000
#define DIN 128
#define HID 96
#define DOUT 32
static constexpr float BN_EPS = 1e-5f;
#define SCAN_NB ((NN + 255) / 256)   // 391

typedef unsigned short u16;
typedef unsigned int u32;

__device__ __forceinline__ float b2f(u32 lo16) {
    union { u32 u; float f; } c; c.u = lo16 << 16; return c.f;
}
__device__ __forceinline__ u16 f2b(float f) {
    union { float f; u32 u; } c; c.f = f;
    return (u16)((c.u + 0x7FFFu + ((c.u >> 16) & 1u)) >> 16);
}
// packed edge: bits[31:15] = src (17b), bits[14:0] = fp16 weight (sign bit 0, w>0)
__device__ __forceinline__ u32 pack_edge(int s, float w) {
    __half h = __float2half(w);
    return ((u32)s << 15) | (u32)__half_as_ushort(h);
}
__device__ __forceinline__ int edge_src(u32 pk) { return (int)(pk >> 15); }
__device__ __forceinline__ float edge_wt(u32 pk) {
    return __half2float(__ushort_as_half((u16)(pk & 0x7FFFu)));
}
__device__ __forceinline__ u32 ntload(const u32* p) {
    return __builtin_nontemporal_load(p);
}

// ---------------------------------------------------------------- setup kernels

__global__ void k_init(int* __restrict__ deg) {
    int i = blockIdx.x * 256 + threadIdx.x;
    if (i < NN) deg[i] = 0;
}

// scan phase 1 + dinv fused
__global__ __launch_bounds__(256) void k_scan1(const int* __restrict__ deg,
                                               int* __restrict__ row_start,
                                               int* __restrict__ blksum,
                                               float* __restrict__ dinv) {
    __shared__ int lds[256];
    int t = threadIdx.x;
    int i = blockIdx.x * 256 + t;
    int v = (i < NN) ? deg[i] : 0;
    if (i < NN) dinv[i] = rsqrtf((float)(v + 1));  // +1 self-loop
    lds[t] = v;
    __syncthreads();
#pragma unroll
    for (int off = 1; off < 256; off <<= 1) {
        int add = (t >= off) ? lds[t - off] : 0;
        __syncthreads();
        lds[t] += add;
        __syncthreads();
    }
    if (i < NN) row_start[i] = lds[t] - v;  // exclusive, per-block partial
    if (t == 255) blksum[blockIdx.x] = lds[255];
}

// scans block sums; also zeroes BN-stat accumulators
__global__ __launch_bounds__(512) void k_scan2(int* __restrict__ blksum,
                                               float* __restrict__ meta) {
    __shared__ int lds[512];
    int t = threadIdx.x;
    if (t < 384) meta[t] = 0.f;
    int v = (t < SCAN_NB) ? blksum[t] : 0;
    lds[t] = v;
    __syncthreads();
#pragma unroll
    for (int off = 1; off < 512; off <<= 1) {
        int add = (t >= off) ? lds[t - off] : 0;
        __syncthreads();
        lds[t] += add;
        __syncthreads();
    }
    if (t < SCAN_NB) blksum[t] = lds[t] - v;  // exclusive block offset
}

// fused: blocks [0,VB) finalize row_fin = row_start + blksum; blocks [VB, VB+EB) scatter
// (scatter reads the PARTIAL row_start + blksum, so no race with row_fin writes)
__global__ __launch_bounds__(256) void k_fin_scatter(const int* __restrict__ row_start,
                                                     const int* __restrict__ blksum,
                                                     int* __restrict__ row_fin,
                                                     int fin_blocks,
                                                     const int* __restrict__ src,
                                                     const int* __restrict__ dst,
                                                     const int* __restrict__ rank,
                                                     const float* __restrict__ dinv,
                                                     u32* __restrict__ ewt) {
    int bid = (int)blockIdx.x;
    if (bid < fin_blocks) {
        int i = bid * 256 + (int)threadIdx.x;
        if (i < NN) row_fin[i] = row_start[i] + blksum[i >> 8];
        if (bid == 0 && threadIdx.x == 0) row_fin[NN] = NE;
    } else {
        int e = (bid - fin_blocks) * 256 + (int)threadIdx.x;
        if (e < NE) {
            int d = dst[e];
            int p = row_start[d] + blksum[d >> 8] + rank[e];
            int s = src[e];
            ewt[p] = pack_edge(s, dinv[s]);
        }
    }
}

// ---------------------------------------------------------------- GEMM (fp32 vector)
// Z[M x ND](bf16) = f(X)[M x KD] @ W[KD x ND], f = optional relu(a*x+c) per K-channel.
// Xs transposed to [kk][row] (stride 132) -> xr via 2x ds_read_b128.
template <int KD, int ND, bool FUSE, typename XT>
__device__ __forceinline__ void gemm_body(int bid, const XT* __restrict__ X,
                                          const float* __restrict__ W,
                                          u16* __restrict__ Z,
                                          const float* __restrict__ bnA,
                                          const float* __restrict__ bnC, int M) {
    constexpr int BK = 32;
    constexpr int CT = 16;
    constexpr int CPT = ND / CT;   // 6 (ND=96) or 2 (ND=32)
    constexpr int RPT = 8;         // 16 row-threads * 8 = 128 rows
    constexpr int XS = 132;        // row stride in Xs (pad, 16B-aligned rows)
    __shared__ float Xs[BK * XS];
    __shared__ float Ws[BK * ND];
    __shared__ float As[KD], Cs[KD];

    int tid = threadIdx.x;
    if (FUSE && tid < KD) { As[tid] = bnA[tid]; Cs[tid] = bnC[tid]; }
    int row0 = bid * 128;
    int ct = tid % CT, rt = tid / CT;
    float acc[RPT][CPT];
#pragma unroll
    for (int r = 0; r < RPT; ++r)
#pragma unroll
        for (int c = 0; c < CPT; ++c) acc[r][c] = 0.f;

    for (int k0 = 0; k0 < KD; k0 += BK) {
        __syncthreads();
        if constexpr (sizeof(XT) == 4) {
#pragma unroll
            for (int pass = 0; pass < 4; ++pass) {
                int r = pass * 32 + (tid >> 3);
                int kq = (tid & 7) * 4;
                int grow = row0 + r;
                float4 v = make_float4(0.f, 0.f, 0.f, 0.f);
                if (grow < M) v = *(const float4*)&X[(size_t)grow * KD + k0 + kq];
                if (FUSE) {
                    v.x = fmaxf(fmaf(As[k0 + kq + 0], v.x, Cs[k0 + kq + 0]), 0.f);
                    v.y = fmaxf(fmaf(As[k0 + kq + 1], v.y, Cs[k0 + kq + 1]), 0.f);
                    v.z = fmaxf(fmaf(As[k0 + kq + 2], v.z, Cs[k0 + kq + 2]), 0.f);
                    v.w = fmaxf(fmaf(As[k0 + kq + 3], v.w, Cs[k0 + kq + 3]), 0.f);
                }
                Xs[(kq + 0) * XS + r] = v.x;
                Xs[(kq + 1) * XS + r] = v.y;
                Xs[(kq + 2) * XS + r] = v.z;
                Xs[(kq + 3) * XS + r] = v.w;
            }
        } else {
#pragma unroll
            for (int pass = 0; pass < 2; ++pass) {
                int r = pass * 64 + (tid >> 2);
                int kq = (tid & 3) * 8;
                int grow = row0 + r;
                uint4 v = make_uint4(0, 0, 0, 0);
                if (grow < M) v = *(const uint4*)&X[(size_t)grow * KD + k0 + kq];
                u32 w[4] = {v.x, v.y, v.z, v.w};
#pragma unroll
                for (int q = 0; q < 4; ++q) {
                    float lo = b2f(w[q] & 0xFFFFu);
                    float hi = b2f(w[q] >> 16);
                    if (FUSE) {
                        lo = fmaxf(fmaf(As[k0 + kq + 2 * q + 0], lo, Cs[k0 + kq + 2 * q + 0]), 0.f);
                        hi = fmaxf(fmaf(As[k0 + kq + 2 * q + 1], hi, Cs[k0 + kq + 2 * q + 1]), 0.f);
                    }
                    Xs[(kq + 2 * q + 0) * XS + r] = lo;
                    Xs[(kq + 2 * q + 1) * XS + r] = hi;
                }
            }
        }
#pragma unroll
        for (int f = tid; f < BK * ND / 4; f += 256) {
            int kk = f / (ND / 4);
            int c4 = (f % (ND / 4)) * 4;
            *(float4*)&Ws[kk * ND + c4] = *(const float4*)&W[(size_t)(k0 + kk) * ND + c4];
        }
        __syncthreads();
#pragma unroll
        for (int kk = 0; kk < BK; ++kk) {
            float4 x0 = *(const float4*)&Xs[kk * XS + rt * 8];
            float4 x1 = *(const float4*)&Xs[kk * XS + rt * 8 + 4];
            float xr[RPT] = {x0.x, x0.y, x0.z, x0.w, x1.x, x1.y, x1.z, x1.w};
            float wc[CPT];
#pragma unroll
            for (int c = 0; c < CPT; ++c) wc[c] = Ws[kk * ND + ct * CPT + c];
#pragma unroll
            for (int r = 0; r < RPT; ++r)
#pragma unroll
                for (int c = 0; c < CPT; ++c) acc[r][c] = fmaf(xr[r], wc[c], acc[r][c]);
        }
    }
#pragma unroll
    for (int r = 0; r < RPT; ++r) {
        int grow = row0 + rt * RPT + r;
        if (grow < M) {
#pragma unroll
            for (int c = 0; c < CPT; c += 2) {
                u32 pk = (u32)f2b(acc[r][c]) | ((u32)f2b(acc[r][c + 1]) << 16);
                *(u32*)&Z[(size_t)grow * ND + ct * CPT + c] = pk;
            }
        }
    }
}

template <int KD, int ND, bool FUSE, typename XT>
__global__ __launch_bounds__(256) void k_gemm(const XT* __restrict__ X,
                                              const float* __restrict__ W,
                                              u16* __restrict__ Z,
                                              const float* __restrict__ bnA,
                                              const float* __restrict__ bnC, int M) {
    gemm_body<KD, ND, FUSE, XT>(blockIdx.x, X, W, Z, bnA, bnC, M);
}

// fused: blocks [0, gemm_blocks) do GEMM1; the rest do the edge histogram
__global__ __launch_bounds__(256) void k_gemm1_hist(const float* __restrict__ X,
                                                    const float* __restrict__ W,
                                                    u16* __restrict__ Z, int M,
                                                    int gemm_blocks,
                                                    const int* __restrict__ dst,
                                                    int* __restrict__ deg,
                                                    int* __restrict__ rank) {
    if ((int)blockIdx.x < gemm_blocks) {
        gemm_body<DIN, HID, false, float>(blockIdx.x, X, W, Z, nullptr, nullptr, M);
    } else {
        int e = ((int)blockIdx.x - gemm_blocks) * 256 + (int)threadIdx.x;
        if (e < NE) rank[e] = atomicAdd(&deg[dst[e]], 1);
    }
}

// ---------------------------------------------------------------- aggregation, 96ch (bf16)
// one wave per node; lane l<48 gathers the row's dword l. Two-chunk pipeline (16 in flight).
// z gathers + ewt reads are NON-TEMPORAL (bypass L1 — 19.2MB working set thrashes 32KB L1).
__global__ __launch_bounds__(256) void k_agg96(const u16* __restrict__ Z,
                                               u16* __restrict__ H,
                                               const float* __restrict__ bias,
                                               const int* __restrict__ row_start,
                                               const u32* __restrict__ ewt,
                                               const float* __restrict__ dinv,
                                               float* __restrict__ gsum,
                                               float* __restrict__ gsq) {
    __shared__ float ssum[96], ssq[96];
    int tid = threadIdx.x;
    if (tid < 96) { ssum[tid] = 0.f; ssq[tid] = 0.f; }
    __syncthreads();
    int wid = tid >> 6, lane = tid & 63;
    bool act = lane < 48;
    int l = act ? lane : 47;
    const u32* zu = (const u32*)Z;          // row stride 48 dwords
    float b0 = bias[2 * l], b1 = bias[2 * l + 1];
    float lsum0 = 0.f, lsq0 = 0.f, lsum1 = 0.f, lsq1 = 0.f;
    const int stride = gridDim.x * 4;

    int n = blockIdx.x * 4 + wid;
    int e0 = 0, e1 = 0;
    u32 pr = 0;
    if (n < NN) {
        e0 = row_start[n]; e1 = row_start[n + 1];
        if (e0 + lane < e1) pr = ntload(&ewt[e0 + lane]);
    }
    while (n < NN) {
        int n2 = n + stride;
        int e0n = 0, e1n = 0;
        if (n2 < NN) { e0n = row_start[n2]; e1n = row_start[n2 + 1]; }

        float dn = dinv[n];
        u32 uself = zu[(size_t)n * 48 + l];
        float a0a = dn * b2f(uself & 0xFFFFu);
        float a1a = dn * b2f(uself >> 16);
        float a0b = 0.f, a1b = 0.f;

        u32 plv = pr;

        u32 prn = 0;
        if (n2 < NN && e0n + lane < e1n) prn = ntload(&ewt[e0n + lane]);

        int m = e1 - e0;
        if (m <= 64) {
            int K = (m + 7) >> 3;
            u32 uA[8], uB[8];
            float wA[8], wB[8];
            {
#pragma unroll
                for (int q = 0; q < 8; ++q) {
                    bool v = q < m;
                    u32 pk = __shfl(plv, v ? q : 0);
                    wA[q] = v ? edge_wt(pk) : 0.f;
                    uA[q] = ntload(&zu[(size_t)edge_src(pk) * 48 + l]);
                }
            }
            for (int c = 0; c < K; ++c) {
                if ((c & 1) == 0) {
                    if (c + 1 < K) {
#pragma unroll
                        for (int q = 0; q < 8; ++q) {
                            int j = (c + 1) * 8 + q;
                            bool v = j < m;
                            u32 pk = __shfl(plv, v ? j : 0);
                            wB[q] = v ? edge_wt(pk) : 0.f;
                            uB[q] = ntload(&zu[(size_t)edge_src(pk) * 48 + l]);
                        }
                    }
#pragma unroll
                    for (int q = 0; q < 8; q += 2) {
                        a0a = fmaf(wA[q], b2f(uA[q] & 0xFFFFu), a0a);
                        a1a = fmaf(wA[q], b2f(uA[q] >> 16), a1a);
                        a0b = fmaf(wA[q + 1], b2f(uA[q + 1] & 0xFFFFu), a0b);
                        a1b = fmaf(wA[q + 1], b2f(uA[q + 1] >> 16), a1b);
                    }
                } else {
                    if (c + 1 < K) {
#pragma unroll
                        for (int q = 0; q < 8; ++q) {
                            int j = (c + 1) * 8 + q;
                            bool v = j < m;
                            u32 pk = __shfl(plv, v ? j : 0);
                            wA[q] = v ? edge_wt(pk) : 0.f;
                            uA[q] = ntload(&zu[(size_t)edge_src(pk) * 48 + l]);
                        }
                    }
#pragma unroll
                    for (int q = 0; q < 8; q += 2) {
                        a0a = fmaf(wB[q], b2f(uB[q] & 0xFFFFu), a0a);
                        a1a = fmaf(wB[q], b2f(uB[q] >> 16), a1a);
                        a0b = fmaf(wB[q + 1], b2f(uB[q + 1] & 0xFFFFu), a0b);
                        a1b = fmaf(wB[q + 1], b2f(uB[q + 1] >> 16), a1b);
                    }
                }
            }
        } else {
            // rare: deg > 64, windowed fallback
            u32 cw = plv;
            for (int eb = e0; eb < e1; eb += 64) {
                if (eb != e0) {
                    int idx = eb + lane;
                    cw = (idx < e1) ? ntload(&ewt[idx]) : 0;
                }
                int mm = e1 - eb; if (mm > 64) mm = 64;
                for (int j = 0; j < mm; ++j) {
                    u32 pk = __shfl(cw, j);
                    float w = edge_wt(pk);
                    u32 u = ntload(&zu[(size_t)edge_src(pk) * 48 + l]);
                    a0a = fmaf(w, b2f(u & 0xFFFFu), a0a);
                    a1a = fmaf(w, b2f(u >> 16), a1a);
                }
            }
        }
        float h0 = fmaf(dn, a0a + a0b, b0);
        float h1 = fmaf(dn, a1a + a1b, b1);
        if (act) {
            u32 pk = (u32)f2b(h0) | ((u32)f2b(h1) << 16);
            ((u32*)H)[(size_t)n * 48 + l] = pk;
            lsum0 += h0; lsq0 = fmaf(h0, h0, lsq0);
            lsum1 += h1; lsq1 = fmaf(h1, h1, lsq1);
        }
        n = n2; e0 = e0n; e1 = e1n; pr = prn;
    }
    if (act) {
        atomicAdd(&ssum[2 * l], lsum0); atomicAdd(&ssq[2 * l], lsq0);
        atomicAdd(&ssum[2 * l + 1], lsum1); atomicAdd(&ssq[2 * l + 1], lsq1);
    }
    __syncthreads();
    if (tid < 96) { atomicAdd(&gsum[tid], ssum[tid]); atomicAdd(&gsq[tid], ssq[tid]); }
}

__global__ void k_bncoef(const float* __restrict__ gsum, const float* __restrict__ gsq,
                         const float* __restrict__ g, const float* __restrict__ be,
                         float* __restrict__ bnA, float* __restrict__ bnC) {
    int c = threadIdx.x;
    if (c < 96) {
        float mean = gsum[c] * (1.f / NN);
        float var = gsq[c] * (1.f / NN) - mean * mean;
        float inv = rsqrtf(var + BN_EPS);
        float a = g[c] * inv;
        bnA[c] = a;
        bnC[c] = fmaf(-a, mean, be[c]);
    }
}

// ---------------------------------------------------------------- final agg + log_softmax
// 4 nodes per wave (16-lane groups). Chunk-8 gathers (adaptive), non-temporal.
__global__ __launch_bounds__(256) void k_agg32_lsm(const u16* __restrict__ Z,
                                                   float* __restrict__ Out,
                                                   const float* __restrict__ bias,
                                                   const int* __restrict__ row_start,
                                                   const u32* __restrict__ ewt,
                                                   const float* __restrict__ dinv) {
    int tid = threadIdx.x;
    int wid = tid >> 6, lane = tid & 63;
    int g = lane >> 4, sl = lane & 15;
    const u32* zu = (const u32*)Z;  // row stride 16 dwords
    float b0 = bias[2 * sl], b1 = bias[2 * sl + 1];
    int stride = gridDim.x * 16;
    for (int n0 = (blockIdx.x * 4 + wid) * 4; n0 < NN; n0 += stride) {
        int n = n0 + g;
        bool vn = n < NN;
        float dn = vn ? dinv[n] : 0.f;
        u32 uself = vn ? zu[(size_t)n * 16 + sl] : 0;
        float a0a = dn * b2f(uself & 0xFFFFu);
        float a1a = dn * b2f(uself >> 16);
        float a0b = 0.f, a1b = 0.f;
        int e0 = vn ? row_start[n] : 0, e1 = vn ? row_start[n + 1] : 0;
        for (int eb = e0; eb < e1; eb += 16) {
            int mm = e1 - eb; if (mm > 16) mm = 16;
            int idx = eb + sl;
            u32 plv = (idx < e1) ? ntload(&ewt[idx]) : 0;
            for (int j = 0; j < mm; j += 8) {
                int rem = mm - j; if (rem > 8) rem = 8;
                u32 u_[8]; float w_[8];
#pragma unroll
                for (int q = 0; q < 8; ++q) {
                    bool v = q < rem;
                    u32 pk = __shfl(plv, j + (v ? q : 0), 16);
                    w_[q] = v ? edge_wt(pk) : 0.f;
                    u_[q] = ntload(&zu[(size_t)edge_src(pk) * 16 + sl]);
                }
#pragma unroll
                for (int q = 0; q < 8; q += 2) {
                    a0a = fmaf(w_[q], b2f(u_[q] & 0xFFFFu), a0a);
                    a1a = fmaf(w_[q], b2f(u_[q] >> 16), a1a);
                    a0b = fmaf(w_[q + 1], b2f(u_[q + 1] & 0xFFFFu), a0b);
                    a1b = fmaf(w_[q + 1], b2f(u_[q + 1] >> 16), a1b);
                }
            }
        }
        float v0 = fmaf(dn, a0a + a0b, b0);
        float v1 = fmaf(dn, a1a + a1b, b1);
        float mx = fmaxf(v0, v1);
#pragma unroll
        for (int off = 8; off; off >>= 1) mx = fmaxf(mx, __shfl_xor(mx, off, 16));
        float ex = __expf(v0 - mx) + __expf(v1 - mx);
#pragma unroll
        for (int off = 8; off; off >>= 1) ex += __shfl_xor(ex, off, 16);
        float lse = mx + __logf(ex);
        if (vn) {
            float2 o = make_float2(v0 - lse, v1 - lse);
            *(float2*)&Out[(size_t)n * 32 + 2 * sl] = o;
        }
    }
}

// ---------------------------------------------------------------- launch

extern "C" void kernel_launch(void* const* d_in, const int* in_sizes, int n_in,
                              void* d_out, int out_size, void* d_ws, size_t ws_size,
                              hipStream_t stream) {
    const float* x  = (const float*)d_in[0];
    const int* ei   = (const int*)d_in[1];   // [2, NE]: src then dst
    const float* W1 = (const float*)d_in[2];
    const float* b1 = (const float*)d_in[3];
    const float* W2 = (const float*)d_in[4];
    const float* b2 = (const float*)d_in[5];
    const float* W3 = (const float*)d_in[6];
    const float* b3 = (const float*)d_in[7];
    const float* g1 = (const float*)d_in[8];
    const float* be1 = (const float*)d_in[9];
    const float* g2 = (const float*)d_in[10];
    const float* be2 = (const float*)d_in[11];
    float* out = (float*)d_out;

    const int* src = ei;
    const int* dst = ei + NE;

    char* p = (char*)d_ws;
    size_t off = 0;
    auto take = [&](size_t bytes) {
        char* r = p + off;
        off = (off + bytes + 255) & ~(size_t)255;
        return r;
    };
    float* dinv      = (float*)take(NN * 4);
    int*   deg       = (int*)take(NN * 4);
    int*   row_start = (int*)take((NN + 1) * 4);   // partial (per-block) scan
    int*   row_fin   = (int*)take((NN + 1) * 4);   // finalized CSR offsets
    int*   blksum    = (int*)take(SCAN_NB * 4);
    int*   rank      = (int*)take((size_t)NE * 4);
    u32*   ewt       = (u32*)take((size_t)NE * 4);
    float* meta      = (float*)take(768 * 4);
    u16*   bufA      = (u16*)take((size_t)NN * HID * 2);
    u16*   bufB      = (u16*)take((size_t)NN * HID * 2);

    float* sum1 = meta + 0,   *sq1 = meta + 96;
    float* sum2 = meta + 192, *sq2 = meta + 288;
    float* bnA1 = meta + 384, *bnC1 = meta + 480;
    float* bnA2 = meta + 576, *bnC2 = meta + 672;

    const int EB = (NE + 255) / 256;   // 3125
    const int VB = (NN + 255) / 256;   // 391
    const int GB = (NN + 127) / 128;   // 782 GEMM blocks
    const int AB = 2048;               // agg blocks: 8 per CU

    k_init<<<VB, 256, 0, stream>>>(deg);
    // GEMM1 (independent of graph setup) fused with edge histogram
    k_gemm1_hist<<<GB + EB, 256, 0, stream>>>(x, W1, bufA, NN, GB, dst, deg, rank);
    k_scan1<<<SCAN_NB, 256, 0, stream>>>(deg, row_start, blksum, dinv);
    k_scan2<<<1, 512, 0, stream>>>(blksum, meta);
    k_fin_scatter<<<VB + EB, 256, 0, stream>>>(row_start, blksum, row_fin, VB,
                                               src, dst, rank, dinv, ewt);

    // layer 1 aggregation (z1 already in bufA)
    k_agg96<<<AB, 256, 0, stream>>>(bufA, bufB, b1, row_fin, ewt, dinv, sum1, sq1);
    k_bncoef<<<1, 128, 0, stream>>>(sum1, sq1, g1, be1, bnA1, bnC1);

    // layer 2: z = relu(bn(h1))@W2 ; h2 = agg(z)+b2 (+stats)
    k_gemm<HID, HID, true, u16><<<GB, 256, 0, stream>>>(bufB, W2, bufA, bnA1, bnC1, NN);
    k_agg96<<<AB, 256, 0, stream>>>(bufA, bufB, b2, row_fin, ewt, dinv, sum2, sq2);
    k_bncoef<<<1, 128, 0, stream>>>(sum2, sq2, g2, be2, bnA2, bnC2);

    // layer 3: z = relu(bn(h2))@W3 ; out = log_softmax(agg(z)+b3)
    k_gemm<HID, DOUT, true, u16><<<GB, 256, 0, stream>>>(bufB, W3, bufA, bnA2, bnC2, NN);
    k_agg32_lsm<<<AB, 256, 0, stream>>>(bufA, out, b3, row_fin, ewt, dinv);

    (void)in_sizes; (void)n_in; (void)out_size; (void)ws_size;
}

// Round 10
// 432.181 us; speedup vs baseline: 1.0836x; 1.0836x over previous
//
#include <hip/hip_runtime.h>
#include <hip/hip_fp16.h>
#include <cstddef>

#define NN 100000
#define NE 800000
#define DIN 128
#define HID 96
#define DOUT 32
static constexpr float BN_EPS = 1e-5f;
#define SCAN_NB ((NN + 255) / 256)   // 391

typedef unsigned short u16;
typedef unsigned int u32;

__device__ __forceinline__ float b2f(u32 lo16) {
    union { u32 u; float f; } c; c.u = lo16 << 16; return c.f;
}
__device__ __forceinline__ u16 f2b(float f) {
    union { float f; u32 u; } c; c.f = f;
    return (u16)((c.u + 0x7FFFu + ((c.u >> 16) & 1u)) >> 16);
}
// packed edge: bits[31:15] = src (17b), bits[14:0] = fp16 weight (sign bit 0, w>0)
__device__ __forceinline__ u32 pack_edge(int s, float w) {
    __half h = __float2half(w);
    return ((u32)s << 15) | (u32)__half_as_ushort(h);
}
__device__ __forceinline__ int edge_src(u32 pk) { return (int)(pk >> 15); }
__device__ __forceinline__ float edge_wt(u32 pk) {
    return __half2float(__ushort_as_half((u16)(pk & 0x7FFFu)));
}

// ---------------------------------------------------------------- setup kernels

__global__ void k_init(int* __restrict__ deg) {
    int i = blockIdx.x * 256 + threadIdx.x;
    if (i < NN) deg[i] = 0;
}

// scan phase 1 + dinv fused
__global__ __launch_bounds__(256) void k_scan1(const int* __restrict__ deg,
                                               int* __restrict__ row_start,
                                               int* __restrict__ blksum,
                                               float* __restrict__ dinv) {
    __shared__ int lds[256];
    int t = threadIdx.x;
    int i = blockIdx.x * 256 + t;
    int v = (i < NN) ? deg[i] : 0;
    if (i < NN) dinv[i] = rsqrtf((float)(v + 1));  // +1 self-loop
    lds[t] = v;
    __syncthreads();
#pragma unroll
    for (int off = 1; off < 256; off <<= 1) {
        int add = (t >= off) ? lds[t - off] : 0;
        __syncthreads();
        lds[t] += add;
        __syncthreads();
    }
    if (i < NN) row_start[i] = lds[t] - v;  // exclusive, per-block partial
    if (t == 255) blksum[blockIdx.x] = lds[255];
}

// scans block sums; also zeroes BN-stat accumulators
__global__ __launch_bounds__(512) void k_scan2(int* __restrict__ blksum,
                                               float* __restrict__ meta) {
    __shared__ int lds[512];
    int t = threadIdx.x;
    if (t < 384) meta[t] = 0.f;
    int v = (t < SCAN_NB) ? blksum[t] : 0;
    lds[t] = v;
    __syncthreads();
#pragma unroll
    for (int off = 1; off < 512; off <<= 1) {
        int add = (t >= off) ? lds[t - off] : 0;
        __syncthreads();
        lds[t] += add;
        __syncthreads();
    }
    if (t < SCAN_NB) blksum[t] = lds[t] - v;  // exclusive block offset
}

// fused: blocks [0,VB) finalize row_fin = row_start + blksum; blocks [VB, VB+EB) scatter
__global__ __launch_bounds__(256) void k_fin_scatter(const int* __restrict__ row_start,
                                                     const int* __restrict__ blksum,
                                                     int* __restrict__ row_fin,
                                                     int fin_blocks,
                                                     const int* __restrict__ src,
                                                     const int* __restrict__ dst,
                                                     const int* __restrict__ rank,
                                                     const float* __restrict__ dinv,
                                                     u32* __restrict__ ewt) {
    int bid = (int)blockIdx.x;
    if (bid < fin_blocks) {
        int i = bid * 256 + (int)threadIdx.x;
        if (i < NN) row_fin[i] = row_start[i] + blksum[i >> 8];
        if (bid == 0 && threadIdx.x == 0) row_fin[NN] = NE;
    } else {
        int e = (bid - fin_blocks) * 256 + (int)threadIdx.x;
        if (e < NE) {
            int d = dst[e];
            int p = row_start[d] + blksum[d >> 8] + rank[e];
            int s = src[e];
            ewt[p] = pack_edge(s, dinv[s]);
        }
    }
}

// ---------------------------------------------------------------- GEMM (fp32 vector)
// Z[M x ND](bf16) = f(X)[M x KD] @ W[KD x ND], f = optional relu(a*x+c) per K-channel.
// Xs transposed to [kk][row] (stride 132) -> xr via 2x ds_read_b128.
template <int KD, int ND, bool FUSE, typename XT>
__device__ __forceinline__ void gemm_body(int bid, const XT* __restrict__ X,
                                          const float* __restrict__ W,
                                          u16* __restrict__ Z,
                                          const float* __restrict__ bnA,
                                          const float* __restrict__ bnC, int M) {
    constexpr int BK = 32;
    constexpr int CT = 16;
    constexpr int CPT = ND / CT;   // 6 (ND=96) or 2 (ND=32)
    constexpr int RPT = 8;         // 16 row-threads * 8 = 128 rows
    constexpr int XS = 132;        // row stride in Xs (pad, 16B-aligned rows)
    __shared__ float Xs[BK * XS];
    __shared__ float Ws[BK * ND];
    __shared__ float As[KD], Cs[KD];

    int tid = threadIdx.x;
    if (FUSE && tid < KD) { As[tid] = bnA[tid]; Cs[tid] = bnC[tid]; }
    int row0 = bid * 128;
    int ct = tid % CT, rt = tid / CT;
    float acc[RPT][CPT];
#pragma unroll
    for (int r = 0; r < RPT; ++r)
#pragma unroll
        for (int c = 0; c < CPT; ++c) acc[r][c] = 0.f;

    for (int k0 = 0; k0 < KD; k0 += BK) {
        __syncthreads();
        if constexpr (sizeof(XT) == 4) {
#pragma unroll
            for (int pass = 0; pass < 4; ++pass) {
                int r = pass * 32 + (tid >> 3);
                int kq = (tid & 7) * 4;
                int grow = row0 + r;
                float4 v = make_float4(0.f, 0.f, 0.f, 0.f);
                if (grow < M) v = *(const float4*)&X[(size_t)grow * KD + k0 + kq];
                if (FUSE) {
                    v.x = fmaxf(fmaf(As[k0 + kq + 0], v.x, Cs[k0 + kq + 0]), 0.f);
                    v.y = fmaxf(fmaf(As[k0 + kq + 1], v.y, Cs[k0 + kq + 1]), 0.f);
                    v.z = fmaxf(fmaf(As[k0 + kq + 2], v.z, Cs[k0 + kq + 2]), 0.f);
                    v.w = fmaxf(fmaf(As[k0 + kq + 3], v.w, Cs[k0 + kq + 3]), 0.f);
                }
                Xs[(kq + 0) * XS + r] = v.x;
                Xs[(kq + 1) * XS + r] = v.y;
                Xs[(kq + 2) * XS + r] = v.z;
                Xs[(kq + 3) * XS + r] = v.w;
            }
        } else {
#pragma unroll
            for (int pass = 0; pass < 2; ++pass) {
                int r = pass * 64 + (tid >> 2);
                int kq = (tid & 3) * 8;
                int grow = row0 + r;
                uint4 v = make_uint4(0, 0, 0, 0);
                if (grow < M) v = *(const uint4*)&X[(size_t)grow * KD + k0 + kq];
                u32 w[4] = {v.x, v.y, v.z, v.w};
#pragma unroll
                for (int q = 0; q < 4; ++q) {
                    float lo = b2f(w[q] & 0xFFFFu);
                    float hi = b2f(w[q] >> 16);
                    if (FUSE) {
                        lo = fmaxf(fmaf(As[k0 + kq + 2 * q + 0], lo, Cs[k0 + kq + 2 * q + 0]), 0.f);
                        hi = fmaxf(fmaf(As[k0 + kq + 2 * q + 1], hi, Cs[k0 + kq + 2 * q + 1]), 0.f);
                    }
                    Xs[(kq + 2 * q + 0) * XS + r] = lo;
                    Xs[(kq + 2 * q + 1) * XS + r] = hi;
                }
            }
        }
#pragma unroll
        for (int f = tid; f < BK * ND / 4; f += 256) {
            int kk = f / (ND / 4);
            int c4 = (f % (ND / 4)) * 4;
            *(float4*)&Ws[kk * ND + c4] = *(const float4*)&W[(size_t)(k0 + kk) * ND + c4];
        }
        __syncthreads();
#pragma unroll
        for (int kk = 0; kk < BK; ++kk) {
            float4 x0 = *(const float4*)&Xs[kk * XS + rt * 8];
            float4 x1 = *(const float4*)&Xs[kk * XS + rt * 8 + 4];
            float xr[RPT] = {x0.x, x0.y, x0.z, x0.w, x1.x, x1.y, x1.z, x1.w};
            float wc[CPT];
#pragma unroll
            for (int c = 0; c < CPT; ++c) wc[c] = Ws[kk * ND + ct * CPT + c];
#pragma unroll
            for (int r = 0; r < RPT; ++r)
#pragma unroll
                for (int c = 0; c < CPT; ++c) acc[r][c] = fmaf(xr[r], wc[c], acc[r][c]);
        }
    }
#pragma unroll
    for (int r = 0; r < RPT; ++r) {
        int grow = row0 + rt * RPT + r;
        if (grow < M) {
#pragma unroll
            for (int c = 0; c < CPT; c += 2) {
                u32 pk = (u32)f2b(acc[r][c]) | ((u32)f2b(acc[r][c + 1]) << 16);
                *(u32*)&Z[(size_t)grow * ND + ct * CPT + c] = pk;
            }
        }
    }
}

template <int KD, int ND, bool FUSE, typename XT>
__global__ __launch_bounds__(256) void k_gemm(const XT* __restrict__ X,
                                              const float* __restrict__ W,
                                              u16* __restrict__ Z,
                                              const float* __restrict__ bnA,
                                              const float* __restrict__ bnC, int M) {
    gemm_body<KD, ND, FUSE, XT>(blockIdx.x, X, W, Z, bnA, bnC, M);
}

// fused: blocks [0, gemm_blocks) do GEMM1; the rest do the edge histogram
__global__ __launch_bounds__(256) void k_gemm1_hist(const float* __restrict__ X,
                                                    const float* __restrict__ W,
                                                    u16* __restrict__ Z, int M,
                                                    int gemm_blocks,
                                                    const int* __restrict__ dst,
                                                    int* __restrict__ deg,
                                                    int* __restrict__ rank) {
    if ((int)blockIdx.x < gemm_blocks) {
        gemm_body<DIN, HID, false, float>(blockIdx.x, X, W, Z, nullptr, nullptr, M);
    } else {
        int e = ((int)blockIdx.x - gemm_blocks) * 256 + (int)threadIdx.x;
        if (e < NE) rank[e] = atomicAdd(&deg[dst[e]], 1);
    }
}

// ---------------------------------------------------------------- aggregation, 96ch (bf16)
// one wave per node; lane l<48 gathers the row's dword l. Two-chunk pipeline (16 in flight).
// Plain (L1-cached) loads: nt bypass measured WORSE (R8: 86->108us, FETCH +8%).
__global__ __launch_bounds__(256) void k_agg96(const u16* __restrict__ Z,
                                               u16* __restrict__ H,
                                               const float* __restrict__ bias,
                                               const int* __restrict__ row_start,
                                               const u32* __restrict__ ewt,
                                               const float* __restrict__ dinv,
                                               float* __restrict__ gsum,
                                               float* __restrict__ gsq) {
    __shared__ float ssum[96], ssq[96];
    int tid = threadIdx.x;
    if (tid < 96) { ssum[tid] = 0.f; ssq[tid] = 0.f; }
    __syncthreads();
    int wid = tid >> 6, lane = tid & 63;
    bool act = lane < 48;
    int l = act ? lane : 47;
    const u32* zu = (const u32*)Z;          // row stride 48 dwords
    float b0 = bias[2 * l], b1 = bias[2 * l + 1];
    float lsum0 = 0.f, lsq0 = 0.f, lsum1 = 0.f, lsq1 = 0.f;
    const int stride = gridDim.x * 4;

    int n = blockIdx.x * 4 + wid;
    int e0 = 0, e1 = 0;
    u32 pr = 0;
    if (n < NN) {
        e0 = row_start[n]; e1 = row_start[n + 1];
        if (e0 + lane < e1) pr = ewt[e0 + lane];
    }
    while (n < NN) {
        int n2 = n + stride;
        int e0n = 0, e1n = 0;
        if (n2 < NN) { e0n = row_start[n2]; e1n = row_start[n2 + 1]; }

        float dn = dinv[n];
        u32 uself = zu[(size_t)n * 48 + l];
        float a0a = dn * b2f(uself & 0xFFFFu);
        float a1a = dn * b2f(uself >> 16);
        float a0b = 0.f, a1b = 0.f;

        u32 plv = pr;

        u32 prn = 0;
        if (n2 < NN && e0n + lane < e1n) prn = ewt[e0n + lane];

        int m = e1 - e0;
        if (m <= 64) {
            int K = (m + 7) >> 3;
            u32 uA[8], uB[8];
            float wA[8], wB[8];
            {
#pragma unroll
                for (int q = 0; q < 8; ++q) {
                    bool v = q < m;
                    u32 pk = __shfl(plv, v ? q : 0);
                    wA[q] = v ? edge_wt(pk) : 0.f;
                    uA[q] = zu[(size_t)edge_src(pk) * 48 + l];
                }
            }
            for (int c = 0; c < K; ++c) {
                if ((c & 1) == 0) {
                    if (c + 1 < K) {
#pragma unroll
                        for (int q = 0; q < 8; ++q) {
                            int j = (c + 1) * 8 + q;
                            bool v = j < m;
                            u32 pk = __shfl(plv, v ? j : 0);
                            wB[q] = v ? edge_wt(pk) : 0.f;
                            uB[q] = zu[(size_t)edge_src(pk) * 48 + l];
                        }
                    }
#pragma unroll
                    for (int q = 0; q < 8; q += 2) {
                        a0a = fmaf(wA[q], b2f(uA[q] & 0xFFFFu), a0a);
                        a1a = fmaf(wA[q], b2f(uA[q] >> 16), a1a);
                        a0b = fmaf(wA[q + 1], b2f(uA[q + 1] & 0xFFFFu), a0b);
                        a1b = fmaf(wA[q + 1], b2f(uA[q + 1] >> 16), a1b);
                    }
                } else {
                    if (c + 1 < K) {
#pragma unroll
                        for (int q = 0; q < 8; ++q) {
                            int j = (c + 1) * 8 + q;
                            bool v = j < m;
                            u32 pk = __shfl(plv, v ? j : 0);
                            wA[q] = v ? edge_wt(pk) : 0.f;
                            uA[q] = zu[(size_t)edge_src(pk) * 48 + l];
                        }
                    }
#pragma unroll
                    for (int q = 0; q < 8; q += 2) {
                        a0a = fmaf(wB[q], b2f(uB[q] & 0xFFFFu), a0a);
                        a1a = fmaf(wB[q], b2f(uB[q] >> 16), a1a);
                        a0b = fmaf(wB[q + 1], b2f(uB[q + 1] & 0xFFFFu), a0b);
                        a1b = fmaf(wB[q + 1], b2f(uB[q + 1] >> 16), a1b);
                    }
                }
            }
        } else {
            // rare: deg > 64, windowed fallback
            u32 cw = plv;
            for (int eb = e0; eb < e1; eb += 64) {
                if (eb != e0) {
                    int idx = eb + lane;
                    cw = (idx < e1) ? ewt[idx] : 0;
                }
                int mm = e1 - eb; if (mm > 64) mm = 64;
                for (int j = 0; j < mm; ++j) {
                    u32 pk = __shfl(cw, j);
                    float w = edge_wt(pk);
                    u32 u = zu[(size_t)edge_src(pk) * 48 + l];
                    a0a = fmaf(w, b2f(u & 0xFFFFu), a0a);
                    a1a = fmaf(w, b2f(u >> 16), a1a);
                }
            }
        }
        float h0 = fmaf(dn, a0a + a0b, b0);
        float h1 = fmaf(dn, a1a + a1b, b1);
        if (act) {
            u32 pk = (u32)f2b(h0) | ((u32)f2b(h1) << 16);
            ((u32*)H)[(size_t)n * 48 + l] = pk;
            lsum0 += h0; lsq0 = fmaf(h0, h0, lsq0);
            lsum1 += h1; lsq1 = fmaf(h1, h1, lsq1);
        }
        n = n2; e0 = e0n; e1 = e1n; pr = prn;
    }
    if (act) {
        atomicAdd(&ssum[2 * l], lsum0); atomicAdd(&ssq[2 * l], lsq0);
        atomicAdd(&ssum[2 * l + 1], lsum1); atomicAdd(&ssq[2 * l + 1], lsq1);
    }
    __syncthreads();
    if (tid < 96) { atomicAdd(&gsum[tid], ssum[tid]); atomicAdd(&gsq[tid], ssq[tid]); }
}

__global__ void k_bncoef(const float* __restrict__ gsum, const float* __restrict__ gsq,
                         const float* __restrict__ g, const float* __restrict__ be,
                         float* __restrict__ bnA, float* __restrict__ bnC) {
    int c = threadIdx.x;
    if (c < 96) {
        float mean = gsum[c] * (1.f / NN);
        float var = gsq[c] * (1.f / NN) - mean * mean;
        float inv = rsqrtf(var + BN_EPS);
        float a = g[c] * inv;
        bnA[c] = a;
        bnC[c] = fmaf(-a, mean, be[c]);
    }
}

// ---------------------------------------------------------------- final agg + log_softmax
// 4 nodes per wave (16-lane groups). Chunk-8 adaptive gathers, plain loads.
__global__ __launch_bounds__(256) void k_agg32_lsm(const u16* __restrict__ Z,
                                                   float* __restrict__ Out,
                                                   const float* __restrict__ bias,
                                                   const int* __restrict__ row_start,
                                                   const u32* __restrict__ ewt,
                                                   const float* __restrict__ dinv) {
    int tid = threadIdx.x;
    int wid = tid >> 6, lane = tid & 63;
    int g = lane >> 4, sl = lane & 15;
    const u32* zu = (const u32*)Z;  // row stride 16 dwords
    float b0 = bias[2 * sl], b1 = bias[2 * sl + 1];
    int stride = gridDim.x * 16;
    for (int n0 = (blockIdx.x * 4 + wid) * 4; n0 < NN; n0 += stride) {
        int n = n0 + g;
        bool vn = n < NN;
        float dn = vn ? dinv[n] : 0.f;
        u32 uself = vn ? zu[(size_t)n * 16 + sl] : 0;
        float a0a = dn * b2f(uself & 0xFFFFu);
        float a1a = dn * b2f(uself >> 16);
        float a0b = 0.f, a1b = 0.f;
        int e0 = vn ? row_start[n] : 0, e1 = vn ? row_start[n + 1] : 0;
        for (int eb = e0; eb < e1; eb += 16) {
            int mm = e1 - eb; if (mm > 16) mm = 16;
            int idx = eb + sl;
            u32 plv = (idx < e1) ? ewt[idx] : 0;
            for (int j = 0; j < mm; j += 8) {
                int rem = mm - j; if (rem > 8) rem = 8;
                u32 u_[8]; float w_[8];
#pragma unroll
                for (int q = 0; q < 8; ++q) {
                    bool v = q < rem;
                    u32 pk = __shfl(plv, j + (v ? q : 0), 16);
                    w_[q] = v ? edge_wt(pk) : 0.f;
                    u_[q] = zu[(size_t)edge_src(pk) * 16 + sl];
                }
#pragma unroll
                for (int q = 0; q < 8; q += 2) {
                    a0a = fmaf(w_[q], b2f(u_[q] & 0xFFFFu), a0a);
                    a1a = fmaf(w_[q], b2f(u_[q] >> 16), a1a);
                    a0b = fmaf(w_[q + 1], b2f(u_[q + 1] & 0xFFFFu), a0b);
                    a1b = fmaf(w_[q + 1], b2f(u_[q + 1] >> 16), a1b);
                }
            }
        }
        float v0 = fmaf(dn, a0a + a0b, b0);
        float v1 = fmaf(dn, a1a + a1b, b1);
        float mx = fmaxf(v0, v1);
#pragma unroll
        for (int off = 8; off; off >>= 1) mx = fmaxf(mx, __shfl_xor(mx, off, 16));
        float ex = __expf(v0 - mx) + __expf(v1 - mx);
#pragma unroll
        for (int off = 8; off; off >>= 1) ex += __shfl_xor(ex, off, 16);
        float lse = mx + __logf(ex);
        if (vn) {
            float2 o = make_float2(v0 - lse, v1 - lse);
            *(float2*)&Out[(size_t)n * 32 + 2 * sl] = o;
        }
    }
}

// ---------------------------------------------------------------- launch

extern "C" void kernel_launch(void* const* d_in, const int* in_sizes, int n_in,
                              void* d_out, int out_size, void* d_ws, size_t ws_size,
                              hipStream_t stream) {
    const float* x  = (const float*)d_in[0];
    const int* ei   = (const int*)d_in[1];   // [2, NE]: src then dst
    const float* W1 = (const float*)d_in[2];
    const float* b1 = (const float*)d_in[3];
    const float* W2 = (const float*)d_in[4];
    const float* b2 = (const float*)d_in[5];
    const float* W3 = (const float*)d_in[6];
    const float* b3 = (const float*)d_in[7];
    const float* g1 = (const float*)d_in[8];
    const float* be1 = (const float*)d_in[9];
    const float* g2 = (const float*)d_in[10];
    const float* be2 = (const float*)d_in[11];
    float* out = (float*)d_out;

    const int* src = ei;
    const int* dst = ei + NE;

    char* p = (char*)d_ws;
    size_t off = 0;
    auto take = [&](size_t bytes) {
        char* r = p + off;
        off = (off + bytes + 255) & ~(size_t)255;
        return r;
    };
    float* dinv      = (float*)take(NN * 4);
    int*   deg       = (int*)take(NN * 4);
    int*   row_start = (int*)take((NN + 1) * 4);   // partial (per-block) scan
    int*   row_fin   = (int*)take((NN + 1) * 4);   // finalized CSR offsets
    int*   blksum    = (int*)take(SCAN_NB * 4);
    int*   rank      = (int*)take((size_t)NE * 4);
    u32*   ewt       = (u32*)take((size_t)NE * 4);
    float* meta      = (float*)take(768 * 4);
    u16*   bufA      = (u16*)take((size_t)NN * HID * 2);
    u16*   bufB      = (u16*)take((size_t)NN * HID * 2);

    float* sum1 = meta + 0,   *sq1 = meta + 96;
    float* sum2 = meta + 192, *sq2 = meta + 288;
    float* bnA1 = meta + 384, *bnC1 = meta + 480;
    float* bnA2 = meta + 576, *bnC2 = meta + 672;

    const int EB = (NE + 255) / 256;   // 3125
    const int VB = (NN + 255) / 256;   // 391
    const int GB = (NN + 127) / 128;   // 782 GEMM blocks
    const int AB = 2048;               // agg blocks: 8 per CU

    k_init<<<VB, 256, 0, stream>>>(deg);
    // GEMM1 (independent of graph setup) fused with edge histogram
    k_gemm1_hist<<<GB + EB, 256, 0, stream>>>(x, W1, bufA, NN, GB, dst, deg, rank);
    k_scan1<<<SCAN_NB, 256, 0, stream>>>(deg, row_start, blksum, dinv);
    k_scan2<<<1, 512, 0, stream>>>(blksum, meta);
    k_fin_scatter<<<VB + EB, 256, 0, stream>>>(row_start, blksum, row_fin, VB,
                                               src, dst, rank, dinv, ewt);

    // layer 1 aggregation (z1 already in bufA)
    k_agg96<<<AB, 256, 0, stream>>>(bufA, bufB, b1, row_fin, ewt, dinv, sum1, sq1);
    k_bncoef<<<1, 128, 0, stream>>>(sum1, sq1, g1, be1, bnA1, bnC1);

    // layer 2: z = relu(bn(h1))@W2 ; h2 = agg(z)+b2 (+stats)
    k_gemm<HID, HID, true, u16><<<GB, 256, 0, stream>>>(bufB, W2, bufA, bnA1, bnC1, NN);
    k_agg96<<<AB, 256, 0, stream>>>(bufA, bufB, b2, row_fin, ewt, dinv, sum2, sq2);
    k_bncoef<<<1, 128, 0, stream>>>(sum2, sq2, g2, be2, bnA2, bnC2);

    // layer 3: z = relu(bn(h2))@W3 ; out = log_softmax(agg(z)+b3)
    k_gemm<HID, DOUT, true, u16><<<GB, 256, 0, stream>>>(bufB, W3, bufA, bnA2, bnC2, NN);
    k_agg32_lsm<<<AB, 256, 0, stream>>>(bufA, out, b3, row_fin, ewt, dinv);

    (void)in_sizes; (void)n_in; (void)out_size; (void)ws_size;
}

// Round 11
// 428.399 us; speedup vs baseline: 1.0931x; 1.0088x over previous
//
#include <hip/hip_runtime.h>
#include <hip/hip_fp16.h>
#include <cstddef>

#define NN 100000
#define NE 800000
#define DIN 128
#define HID 96
#define DOUT 32
static constexpr float BN_EPS = 1e-5f;
#define SCAN_NB ((NN + 255) / 256)   // 391

typedef unsigned short u16;
typedef unsigned int u32;

__device__ __forceinline__ float b2f(u32 lo16) {
    union { u32 u; float f; } c; c.u = lo16 << 16; return c.f;
}
__device__ __forceinline__ u16 f2b(float f) {
    union { float f; u32 u; } c; c.f = f;
    return (u16)((c.u + 0x7FFFu + ((c.u >> 16) & 1u)) >> 16);
}
// packed edge: bits[31:15] = src (17b), bits[14:0] = fp16 weight (sign bit 0, w>0)
__device__ __forceinline__ u32 pack_edge(int s, float w) {
    __half h = __float2half(w);
    return ((u32)s << 15) | (u32)__half_as_ushort(h);
}
__device__ __forceinline__ int edge_src(u32 pk) { return (int)(pk >> 15); }
__device__ __forceinline__ float edge_wt(u32 pk) {
    return __half2float(__ushort_as_half((u16)(pk & 0x7FFFu)));
}

// ---------------------------------------------------------------- setup kernels

__global__ void k_init(int* __restrict__ deg) {
    int i = blockIdx.x * 256 + threadIdx.x;
    if (i < NN) deg[i] = 0;
}

// scan phase 1 + dinv fused
__global__ __launch_bounds__(256) void k_scan1(const int* __restrict__ deg,
                                               int* __restrict__ row_start,
                                               int* __restrict__ blksum,
                                               float* __restrict__ dinv) {
    __shared__ int lds[256];
    int t = threadIdx.x;
    int i = blockIdx.x * 256 + t;
    int v = (i < NN) ? deg[i] : 0;
    if (i < NN) dinv[i] = rsqrtf((float)(v + 1));  // +1 self-loop
    lds[t] = v;
    __syncthreads();
#pragma unroll
    for (int off = 1; off < 256; off <<= 1) {
        int add = (t >= off) ? lds[t - off] : 0;
        __syncthreads();
        lds[t] += add;
        __syncthreads();
    }
    if (i < NN) row_start[i] = lds[t] - v;  // exclusive, per-block partial
    if (t == 255) blksum[blockIdx.x] = lds[255];
}

// scans block sums; also zeroes BN-stat accumulators
__global__ __launch_bounds__(512) void k_scan2(int* __restrict__ blksum,
                                               float* __restrict__ meta) {
    __shared__ int lds[512];
    int t = threadIdx.x;
    if (t < 384) meta[t] = 0.f;
    int v = (t < SCAN_NB) ? blksum[t] : 0;
    lds[t] = v;
    __syncthreads();
#pragma unroll
    for (int off = 1; off < 512; off <<= 1) {
        int add = (t >= off) ? lds[t - off] : 0;
        __syncthreads();
        lds[t] += add;
        __syncthreads();
    }
    if (t < SCAN_NB) blksum[t] = lds[t] - v;  // exclusive block offset
}

// fused: blocks [0,VB) finalize row_fin; blocks [VB, VB+EB2) scatter 2 edges/thread
__global__ __launch_bounds__(256) void k_fin_scatter(const int* __restrict__ row_start,
                                                     const int* __restrict__ blksum,
                                                     int* __restrict__ row_fin,
                                                     int fin_blocks,
                                                     const int* __restrict__ src,
                                                     const int* __restrict__ dst,
                                                     const int* __restrict__ rank,
                                                     const float* __restrict__ dinv,
                                                     u32* __restrict__ ewt) {
    int bid = (int)blockIdx.x;
    if (bid < fin_blocks) {
        int i = bid * 256 + (int)threadIdx.x;
        if (i < NN) row_fin[i] = row_start[i] + blksum[i >> 8];
        if (bid == 0 && threadIdx.x == 0) row_fin[NN] = NE;
    } else {
        int base = (bid - fin_blocks) * 512 + (int)threadIdx.x;
#pragma unroll
        for (int h = 0; h < 2; ++h) {
            int e = base + h * 256;
            if (e < NE) {
                int d = dst[e];
                int p = row_start[d] + blksum[d >> 8] + rank[e];
                int s = src[e];
                ewt[p] = pack_edge(s, dinv[s]);
            }
        }
    }
}

// ---------------------------------------------------------------- GEMM (fp32 vector)
// Z[M x ND](bf16) = f(X)[M x KD] @ W[KD x ND].
// FUSE: f = relu(a*x+c) with a,c computed in-prologue from BN stats (gsum,gsq,g,be).
template <int KD, int ND, bool FUSE, typename XT>
__device__ __forceinline__ void gemm_body(int bid, const XT* __restrict__ X,
                                          const float* __restrict__ W,
                                          u16* __restrict__ Z,
                                          const float* __restrict__ gsum,
                                          const float* __restrict__ gsq,
                                          const float* __restrict__ g,
                                          const float* __restrict__ be, int M) {
    constexpr int BK = 32;
    constexpr int CT = 16;
    constexpr int CPT = ND / CT;   // 6 (ND=96) or 2 (ND=32)
    constexpr int RPT = 8;         // 16 row-threads * 8 = 128 rows
    constexpr int XS = 132;        // row stride in Xs (pad, 16B-aligned rows)
    __shared__ float Xs[BK * XS];
    __shared__ float Ws[BK * ND];
    __shared__ float As[FUSE ? KD : 1], Cs[FUSE ? KD : 1];

    int tid = threadIdx.x;
    if (FUSE && tid < KD) {
        float mean = gsum[tid] * (1.f / NN);
        float var = gsq[tid] * (1.f / NN) - mean * mean;
        float inv = rsqrtf(var + BN_EPS);
        float a = g[tid] * inv;
        As[tid] = a;
        Cs[tid] = fmaf(-a, mean, be[tid]);
    }
    int row0 = bid * 128;
    int ct = tid % CT, rt = tid / CT;
    float acc[RPT][CPT];
#pragma unroll
    for (int r = 0; r < RPT; ++r)
#pragma unroll
        for (int c = 0; c < CPT; ++c) acc[r][c] = 0.f;

    for (int k0 = 0; k0 < KD; k0 += BK) {
        __syncthreads();
        if constexpr (sizeof(XT) == 4) {
#pragma unroll
            for (int pass = 0; pass < 4; ++pass) {
                int r = pass * 32 + (tid >> 3);
                int kq = (tid & 7) * 4;
                int grow = row0 + r;
                float4 v = make_float4(0.f, 0.f, 0.f, 0.f);
                if (grow < M) v = *(const float4*)&X[(size_t)grow * KD + k0 + kq];
                if (FUSE) {
                    v.x = fmaxf(fmaf(As[k0 + kq + 0], v.x, Cs[k0 + kq + 0]), 0.f);
                    v.y = fmaxf(fmaf(As[k0 + kq + 1], v.y, Cs[k0 + kq + 1]), 0.f);
                    v.z = fmaxf(fmaf(As[k0 + kq + 2], v.z, Cs[k0 + kq + 2]), 0.f);
                    v.w = fmaxf(fmaf(As[k0 + kq + 3], v.w, Cs[k0 + kq + 3]), 0.f);
                }
                Xs[(kq + 0) * XS + r] = v.x;
                Xs[(kq + 1) * XS + r] = v.y;
                Xs[(kq + 2) * XS + r] = v.z;
                Xs[(kq + 3) * XS + r] = v.w;
            }
        } else {
#pragma unroll
            for (int pass = 0; pass < 2; ++pass) {
                int r = pass * 64 + (tid >> 2);
                int kq = (tid & 3) * 8;
                int grow = row0 + r;
                uint4 v = make_uint4(0, 0, 0, 0);
                if (grow < M) v = *(const uint4*)&X[(size_t)grow * KD + k0 + kq];
                u32 w[4] = {v.x, v.y, v.z, v.w};
#pragma unroll
                for (int q = 0; q < 4; ++q) {
                    float lo = b2f(w[q] & 0xFFFFu);
                    float hi = b2f(w[q] >> 16);
                    if (FUSE) {
                        lo = fmaxf(fmaf(As[k0 + kq + 2 * q + 0], lo, Cs[k0 + kq + 2 * q + 0]), 0.f);
                        hi = fmaxf(fmaf(As[k0 + kq + 2 * q + 1], hi, Cs[k0 + kq + 2 * q + 1]), 0.f);
                    }
                    Xs[(kq + 2 * q + 0) * XS + r] = lo;
                    Xs[(kq + 2 * q + 1) * XS + r] = hi;
                }
            }
        }
#pragma unroll
        for (int f = tid; f < BK * ND / 4; f += 256) {
            int kk = f / (ND / 4);
            int c4 = (f % (ND / 4)) * 4;
            *(float4*)&Ws[kk * ND + c4] = *(const float4*)&W[(size_t)(k0 + kk) * ND + c4];
        }
        __syncthreads();
#pragma unroll
        for (int kk = 0; kk < BK; ++kk) {
            float4 x0 = *(const float4*)&Xs[kk * XS + rt * 8];
            float4 x1 = *(const float4*)&Xs[kk * XS + rt * 8 + 4];
            float xr[RPT] = {x0.x, x0.y, x0.z, x0.w, x1.x, x1.y, x1.z, x1.w};
            float wc[CPT];
#pragma unroll
            for (int c = 0; c < CPT; ++c) wc[c] = Ws[kk * ND + ct * CPT + c];
#pragma unroll
            for (int r = 0; r < RPT; ++r)
#pragma unroll
                for (int c = 0; c < CPT; ++c) acc[r][c] = fmaf(xr[r], wc[c], acc[r][c]);
        }
    }
#pragma unroll
    for (int r = 0; r < RPT; ++r) {
        int grow = row0 + rt * RPT + r;
        if (grow < M) {
#pragma unroll
            for (int c = 0; c < CPT; c += 2) {
                u32 pk = (u32)f2b(acc[r][c]) | ((u32)f2b(acc[r][c + 1]) << 16);
                *(u32*)&Z[(size_t)grow * ND + ct * CPT + c] = pk;
            }
        }
    }
}

template <int KD, int ND, bool FUSE, typename XT>
__global__ __launch_bounds__(256) void k_gemm(const XT* __restrict__ X,
                                              const float* __restrict__ W,
                                              u16* __restrict__ Z,
                                              const float* __restrict__ gsum,
                                              const float* __restrict__ gsq,
                                              const float* __restrict__ g,
                                              const float* __restrict__ be, int M) {
    gemm_body<KD, ND, FUSE, XT>(blockIdx.x, X, W, Z, gsum, gsq, g, be, M);
}

// fused: blocks [0, gemm_blocks) do GEMM1; the rest do the edge histogram (2 edges/thread)
__global__ __launch_bounds__(256) void k_gemm1_hist(const float* __restrict__ X,
                                                    const float* __restrict__ W,
                                                    u16* __restrict__ Z, int M,
                                                    int gemm_blocks,
                                                    const int* __restrict__ dst,
                                                    int* __restrict__ deg,
                                                    int* __restrict__ rank) {
    if ((int)blockIdx.x < gemm_blocks) {
        gemm_body<DIN, HID, false, float>(blockIdx.x, X, W, Z,
                                          nullptr, nullptr, nullptr, nullptr, M);
    } else {
        int base = ((int)blockIdx.x - gemm_blocks) * 512 + (int)threadIdx.x;
#pragma unroll
        for (int h = 0; h < 2; ++h) {
            int e = base + h * 256;
            if (e < NE) rank[e] = atomicAdd(&deg[dst[e]], 1);
        }
    }
}

// ---------------------------------------------------------------- aggregation, 96ch (bf16)
// one wave per node; lane l<48 gathers the row's dword l. Two-chunk pipeline (16 in flight).
// Plain (L1-cached) loads: nt bypass measured WORSE (R8: 86->108us, FETCH +8%).
__global__ __launch_bounds__(256) void k_agg96(const u16* __restrict__ Z,
                                               u16* __restrict__ H,
                                               const float* __restrict__ bias,
                                               const int* __restrict__ row_start,
                                               const u32* __restrict__ ewt,
                                               const float* __restrict__ dinv,
                                               float* __restrict__ gsum,
                                               float* __restrict__ gsq) {
    __shared__ float ssum[96], ssq[96];
    int tid = threadIdx.x;
    if (tid < 96) { ssum[tid] = 0.f; ssq[tid] = 0.f; }
    __syncthreads();
    int wid = tid >> 6, lane = tid & 63;
    bool act = lane < 48;
    int l = act ? lane : 47;
    const u32* zu = (const u32*)Z;          // row stride 48 dwords
    float b0 = bias[2 * l], b1 = bias[2 * l + 1];
    float lsum0 = 0.f, lsq0 = 0.f, lsum1 = 0.f, lsq1 = 0.f;
    const int stride = gridDim.x * 4;

    int n = blockIdx.x * 4 + wid;
    int e0 = 0, e1 = 0;
    u32 pr = 0;
    if (n < NN) {
        e0 = row_start[n]; e1 = row_start[n + 1];
        if (e0 + lane < e1) pr = ewt[e0 + lane];
    }
    while (n < NN) {
        int n2 = n + stride;
        int e0n = 0, e1n = 0;
        if (n2 < NN) { e0n = row_start[n2]; e1n = row_start[n2 + 1]; }

        float dn = dinv[n];
        u32 uself = zu[(size_t)n * 48 + l];
        float a0a = dn * b2f(uself & 0xFFFFu);
        float a1a = dn * b2f(uself >> 16);
        float a0b = 0.f, a1b = 0.f;

        u32 plv = pr;

        u32 prn = 0;
        if (n2 < NN && e0n + lane < e1n) prn = ewt[e0n + lane];

        int m = e1 - e0;
        if (m <= 64) {
            int K = (m + 7) >> 3;
            u32 uA[8], uB[8];
            float wA[8], wB[8];
            {
#pragma unroll
                for (int q = 0; q < 8; ++q) {
                    bool v = q < m;
                    u32 pk = __shfl(plv, v ? q : 0);
                    wA[q] = v ? edge_wt(pk) : 0.f;
                    uA[q] = zu[(size_t)edge_src(pk) * 48 + l];
                }
            }
            for (int c = 0; c < K; ++c) {
                if ((c & 1) == 0) {
                    if (c + 1 < K) {
#pragma unroll
                        for (int q = 0; q < 8; ++q) {
                            int j = (c + 1) * 8 + q;
                            bool v = j < m;
                            u32 pk = __shfl(plv, v ? j : 0);
                            wB[q] = v ? edge_wt(pk) : 0.f;
                            uB[q] = zu[(size_t)edge_src(pk) * 48 + l];
                        }
                    }
#pragma unroll
                    for (int q = 0; q < 8; q += 2) {
                        a0a = fmaf(wA[q], b2f(uA[q] & 0xFFFFu), a0a);
                        a1a = fmaf(wA[q], b2f(uA[q] >> 16), a1a);
                        a0b = fmaf(wA[q + 1], b2f(uA[q + 1] & 0xFFFFu), a0b);
                        a1b = fmaf(wA[q + 1], b2f(uA[q + 1] >> 16), a1b);
                    }
                } else {
                    if (c + 1 < K) {
#pragma unroll
                        for (int q = 0; q < 8; ++q) {
                            int j = (c + 1) * 8 + q;
                            bool v = j < m;
                            u32 pk = __shfl(plv, v ? j : 0);
                            wA[q] = v ? edge_wt(pk) : 0.f;
                            uA[q] = zu[(size_t)edge_src(pk) * 48 + l];
                        }
                    }
#pragma unroll
                    for (int q = 0; q < 8; q += 2) {
                        a0a = fmaf(wB[q], b2f(uB[q] & 0xFFFFu), a0a);
                        a1a = fmaf(wB[q], b2f(uB[q] >> 16), a1a);
                        a0b = fmaf(wB[q + 1], b2f(uB[q + 1] & 0xFFFFu), a0b);
                        a1b = fmaf(wB[q + 1], b2f(uB[q + 1] >> 16), a1b);
                    }
                }
            }
        } else {
            // rare: deg > 64, windowed fallback
            u32 cw = plv;
            for (int eb = e0; eb < e1; eb += 64) {
                if (eb != e0) {
                    int idx = eb + lane;
                    cw = (idx < e1) ? ewt[idx] : 0;
                }
                int mm = e1 - eb; if (mm > 64) mm = 64;
                for (int j = 0; j < mm; ++j) {
                    u32 pk = __shfl(cw, j);
                    float w = edge_wt(pk);
                    u32 u = zu[(size_t)edge_src(pk) * 48 + l];
                    a0a = fmaf(w, b2f(u & 0xFFFFu), a0a);
                    a1a = fmaf(w, b2f(u >> 16), a1a);
                }
            }
        }
        float h0 = fmaf(dn, a0a + a0b, b0);
        float h1 = fmaf(dn, a1a + a1b, b1);
        if (act) {
            u32 pk = (u32)f2b(h0) | ((u32)f2b(h1) << 16);
            ((u32*)H)[(size_t)n * 48 + l] = pk;
            lsum0 += h0; lsq0 = fmaf(h0, h0, lsq0);
            lsum1 += h1; lsq1 = fmaf(h1, h1, lsq1);
        }
        n = n2; e0 = e0n; e1 = e1n; pr = prn;
    }
    if (act) {
        atomicAdd(&ssum[2 * l], lsum0); atomicAdd(&ssq[2 * l], lsq0);
        atomicAdd(&ssum[2 * l + 1], lsum1); atomicAdd(&ssq[2 * l + 1], lsq1);
    }
    __syncthreads();
    if (tid < 96) { atomicAdd(&gsum[tid], ssum[tid]); atomicAdd(&gsq[tid], ssq[tid]); }
}

// ---------------------------------------------------------------- final agg + log_softmax
// 4 nodes per wave (16-lane groups). Chunk-8 adaptive gathers, plain loads.
__global__ __launch_bounds__(256) void k_agg32_lsm(const u16* __restrict__ Z,
                                                   float* __restrict__ Out,
                                                   const float* __restrict__ bias,
                                                   const int* __restrict__ row_start,
                                                   const u32* __restrict__ ewt,
                                                   const float* __restrict__ dinv) {
    int tid = threadIdx.x;
    int wid = tid >> 6, lane = tid & 63;
    int g = lane >> 4, sl = lane & 15;
    const u32* zu = (const u32*)Z;  // row stride 16 dwords
    float b0 = bias[2 * sl], b1 = bias[2 * sl + 1];
    int stride = gridDim.x * 16;
    for (int n0 = (blockIdx.x * 4 + wid) * 4; n0 < NN; n0 += stride) {
        int n = n0 + g;
        bool vn = n < NN;
        float dn = vn ? dinv[n] : 0.f;
        u32 uself = vn ? zu[(size_t)n * 16 + sl] : 0;
        float a0a = dn * b2f(uself & 0xFFFFu);
        float a1a = dn * b2f(uself >> 16);
        float a0b = 0.f, a1b = 0.f;
        int e0 = vn ? row_start[n] : 0, e1 = vn ? row_start[n + 1] : 0;
        for (int eb = e0; eb < e1; eb += 16) {
            int mm = e1 - eb; if (mm > 16) mm = 16;
            int idx = eb + sl;
            u32 plv = (idx < e1) ? ewt[idx] : 0;
            for (int j = 0; j < mm; j += 8) {
                int rem = mm - j; if (rem > 8) rem = 8;
                u32 u_[8]; float w_[8];
#pragma unroll
                for (int q = 0; q < 8; ++q) {
                    bool v = q < rem;
                    u32 pk = __shfl(plv, j + (v ? q : 0), 16);
                    w_[q] = v ? edge_wt(pk) : 0.f;
                    u_[q] = zu[(size_t)edge_src(pk) * 16 + sl];
                }
#pragma unroll
                for (int q = 0; q < 8; q += 2) {
                    a0a = fmaf(w_[q], b2f(u_[q] & 0xFFFFu), a0a);
                    a1a = fmaf(w_[q], b2f(u_[q] >> 16), a1a);
                    a0b = fmaf(w_[q + 1], b2f(u_[q + 1] & 0xFFFFu), a0b);
                    a1b = fmaf(w_[q + 1], b2f(u_[q + 1] >> 16), a1b);
                }
            }
        }
        float v0 = fmaf(dn, a0a + a0b, b0);
        float v1 = fmaf(dn, a1a + a1b, b1);
        float mx = fmaxf(v0, v1);
#pragma unroll
        for (int off = 8; off; off >>= 1) mx = fmaxf(mx, __shfl_xor(mx, off, 16));
        float ex = __expf(v0 - mx) + __expf(v1 - mx);
#pragma unroll
        for (int off = 8; off; off >>= 1) ex += __shfl_xor(ex, off, 16);
        float lse = mx + __logf(ex);
        if (vn) {
            float2 o = make_float2(v0 - lse, v1 - lse);
            *(float2*)&Out[(size_t)n * 32 + 2 * sl] = o;
        }
    }
}

// ---------------------------------------------------------------- launch

extern "C" void kernel_launch(void* const* d_in, const int* in_sizes, int n_in,
                              void* d_out, int out_size, void* d_ws, size_t ws_size,
                              hipStream_t stream) {
    const float* x  = (const float*)d_in[0];
    const int* ei   = (const int*)d_in[1];   // [2, NE]: src then dst
    const float* W1 = (const float*)d_in[2];
    const float* b1 = (const float*)d_in[3];
    const float* W2 = (const float*)d_in[4];
    const float* b2 = (const float*)d_in[5];
    const float* W3 = (const float*)d_in[6];
    const float* b3 = (const float*)d_in[7];
    const float* g1 = (const float*)d_in[8];
    const float* be1 = (const float*)d_in[9];
    const float* g2 = (const float*)d_in[10];
    const float* be2 = (const float*)d_in[11];
    float* out = (float*)d_out;

    const int* src = ei;
    const int* dst = ei + NE;

    char* p = (char*)d_ws;
    size_t off = 0;
    auto take = [&](size_t bytes) {
        char* r = p + off;
        off = (off + bytes + 255) & ~(size_t)255;
        return r;
    };
    float* dinv      = (float*)take(NN * 4);
    int*   deg       = (int*)take(NN * 4);
    int*   row_start = (int*)take((NN + 1) * 4);   // partial (per-block) scan
    int*   row_fin   = (int*)take((NN + 1) * 4);   // finalized CSR offsets
    int*   blksum    = (int*)take(SCAN_NB * 4);
    int*   rank      = (int*)take((size_t)NE * 4);
    u32*   ewt       = (u32*)take((size_t)NE * 4);
    float* meta      = (float*)take(768 * 4);
    u16*   bufA      = (u16*)take((size_t)NN * HID * 2);
    u16*   bufB      = (u16*)take((size_t)NN * HID * 2);

    float* sum1 = meta + 0,   *sq1 = meta + 96;
    float* sum2 = meta + 192, *sq2 = meta + 288;

    const int EB2 = (NE + 511) / 512;  // 1563 (2 edges/thread)
    const int VB = (NN + 255) / 256;   // 391
    const int GB = (NN + 127) / 128;   // 782 GEMM blocks
    const int AB = 2048;               // agg blocks: 8 per CU

    k_init<<<VB, 256, 0, stream>>>(deg);
    // GEMM1 (independent of graph setup) fused with edge histogram
    k_gemm1_hist<<<GB + EB2, 256, 0, stream>>>(x, W1, bufA, NN, GB, dst, deg, rank);
    k_scan1<<<SCAN_NB, 256, 0, stream>>>(deg, row_start, blksum, dinv);
    k_scan2<<<1, 512, 0, stream>>>(blksum, meta);
    k_fin_scatter<<<VB + EB2, 256, 0, stream>>>(row_start, blksum, row_fin, VB,
                                                src, dst, rank, dinv, ewt);

    // layer 1 aggregation (z1 already in bufA)
    k_agg96<<<AB, 256, 0, stream>>>(bufA, bufB, b1, row_fin, ewt, dinv, sum1, sq1);

    // layer 2: z = relu(bn(h1))@W2 (bn coefs computed in-kernel) ; h2 = agg(z)+b2
    k_gemm<HID, HID, true, u16><<<GB, 256, 0, stream>>>(bufB, W2, bufA, sum1, sq1, g1, be1, NN);
    k_agg96<<<AB, 256, 0, stream>>>(bufA, bufB, b2, row_fin, ewt, dinv, sum2, sq2);

    // layer 3: z = relu(bn(h2))@W3 ; out = log_softmax(agg(z)+b3)
    k_gemm<HID, DOUT, true, u16><<<GB, 256, 0, stream>>>(bufB, W3, bufA, sum2, sq2, g2, be2, NN);
    k_agg32_lsm<<<AB, 256, 0, stream>>>(bufA, out, b3, row_fin, ewt, dinv);

    (void)in_sizes; (void)n_in; (void)out_size; (void)ws_size;
}